// Round 16
// baseline (756.899 us; speedup 1.0000x reference)
//
#include <hip/hip_runtime.h>
#include <math.h>

#define BB 8
#define CH 128
#define HH 64
#define WWID 64
#define HIN 62
#define WIN 62
#define SPIN (HIN*WIN)      // 3844
#define HP 66
#define WP 66
#define GP2 70              // padded + 2-guard each side
#define NPIX (BB*HH*WWID)   // 32768
#define ASTRIDE 136         // LDS A-tile row stride in halfs
#define YSTRIDE 35          // phase-2 window col-stride in v8h units
#define XPHALFS ((size_t)BB*GP2*GP2*CH)   // 5,017,600 halfs
#define NBLK 1024

typedef _Float16 v8h __attribute__((ext_vector_type(8)));
typedef float    v4f __attribute__((ext_vector_type(4)));
typedef float    f4a __attribute__((ext_vector_type(4), aligned(4)));

__device__ inline int xcd_swizzle(int bid, int nblk8) {
    return (bid & 7) * nblk8 + (bid >> 3);
}

// Grid barrier, FIXED: poll with pure device-scope atomic LOAD (no RMW).
// Co-residency contract held in R15 (kernel completed): 1024 blocks,
// VGPR 64 <= 128 cap from __launch_bounds__(256,4), LDS 27136 B -> 4 blk/CU.
__device__ inline void gbar(unsigned* cnt) {
    __syncthreads();
    if (threadIdx.x == 0) {
        __hip_atomic_fetch_add(cnt, 1u, __ATOMIC_RELEASE, __HIP_MEMORY_SCOPE_AGENT);
        while (__hip_atomic_load(cnt, __ATOMIC_ACQUIRE, __HIP_MEMORY_SCOPE_AGENT)
               < (unsigned)NBLK)
            __builtin_amdgcn_s_sleep(8);
    }
    __syncthreads();
}

// MFMA core for 4-wave/32-px tiles: wave wv -> mt=wv>>1, ntb=(wv&1)*4
__device__ inline void mfma_loop8(const _Float16* __restrict__ a16,
                                  const _Float16* __restrict__ wp,
                                  v4f acc[4], int t) {
    int lane = t & 63;
    int wv = t >> 6;
    int mt = wv >> 1, ntb = (wv & 1) * 4;
    const _Float16* abase = a16 + (mt * 16 + (lane & 15)) * ASTRIDE + ((lane >> 4) * 8);
    #pragma unroll
    for (int kc = 0; kc < 4; kc++) {
        v8h av = *(const v8h*)(abase + kc * 32);
        #pragma unroll
        for (int j = 0; j < 4; j++) {
            v8h bv = *(const v8h*)(wp + ((size_t)((ntb + j) * 4 + kc) * 64 + lane) * 8);
            acc[j] = __builtin_amdgcn_mfma_f32_16x16x32_f16(av, bv, acc[j], 0, 0, 0);
        }
    }
}

__device__ inline void acc_to_a16_8(_Float16* a16, v4f acc[4], int t) {
    int lane = t & 63, ncol = lane & 15;
    int wv = t >> 6;
    int m0 = (wv >> 1) * 16 + ((lane >> 4) * 4);
    int ntb = (wv & 1) * 4;
    #pragma unroll
    for (int j = 0; j < 4; j++)
        #pragma unroll
        for (int r = 0; r < 4; r++)
            a16[(m0 + r) * ASTRIDE + (ntb + j) * 16 + ncol] = (_Float16)acc[j][r];
}

__global__ __launch_bounds__(256, 4) void mega(
        const float* __restrict__ x,
        const float* __restrict__ conv_w, const float* __restrict__ conv_b,
        const float* __restrict__ in_proj_w, const float* __restrict__ in_b,
        const float* __restrict__ dw_w, const float* __restrict__ dw_b,
        const float* __restrict__ ln_g, const float* __restrict__ ln_b,
        const float* __restrict__ off_w, const float* __restrict__ off_b,
        const float* __restrict__ mask_w, const float* __restrict__ mask_b,
        const float* __restrict__ out_proj_w, const float* __restrict__ out_b,
        _Float16* __restrict__ wp, float* __restrict__ dwT,
        _Float16* __restrict__ y16, _Float16* __restrict__ xpad16,
        float* __restrict__ tapmeta, unsigned* __restrict__ bar,
        float* __restrict__ out) {
    __shared__ char smem[27136];
    int t = threadIdx.x;
    int bid = blockIdx.x;
    const _Float16* wp_conv = wp;
    const _Float16* wp_in   = wp + (size_t)2048 * 8;
    const _Float16* wp_om   = wp + (size_t)4096 * 8;
    const _Float16* wp_out  = wp + (size_t)5888 * 8;

    // ================= phase 0: pack weights + dwT + zero xpad ==============
    if (bid < 31) {
        int tid = bid * 256 + t;                 // 0..7935
        int mat, base;
        if (tid < 2048)      { mat = 0; base = 0; }
        else if (tid < 4096) { mat = 1; base = 2048; }
        else if (tid < 5888) { mat = 2; base = 4096; }
        else                 { mat = 3; base = 5888; }
        int fi = tid - base;
        int nt = fi >> 8, rem = fi & 255, kc = rem >> 6, lane = rem & 63;
        int n = nt * 16 + (lane & 15);
        int kbase = kc * 32 + ((lane >> 4) & 3) * 8;
        _Float16* dst = wp + (size_t)tid * 8;
        #pragma unroll
        for (int j = 0; j < 8; j++) {
            int k = kbase + j;
            float v;
            if (mat == 0)      v = conv_w[n * CH + k];
            else if (mat == 1) v = in_proj_w[k * CH + n];
            else if (mat == 2) v = (n < 72) ? off_w[k * 72 + n]
                                   : (n < 108 ? mask_w[k * 36 + (n - 72)] : 0.f);
            else               v = out_proj_w[k * CH + n];
            dst[j] = (_Float16)v;
        }
    } else if (bid == 31) {
        if (t < 128) {
            #pragma unroll
            for (int tap = 0; tap < 9; tap++) dwT[tap * 128 + t] = dw_w[t * 9 + tap];
        }
    } else {
        size_t nvec = XPHALFS / 8;
        for (size_t i = (size_t)(bid - 32) * 256 + t; i < nvec; i += (size_t)992 * 256)
            *(v8h*)&xpad16[i * 8] = (v8h)(_Float16)0;
    }
    gbar(bar + 0);

    // ================= phase 1: conv1x1(pad=1) + in_proj, 32 px =============
    {
        _Float16* a16 = (_Float16*)smem;                 // 8704 B
        int eff = xcd_swizzle(bid, 128);
        int pix0 = eff * 32;
        int h = (pix0 >> 6) & 63, b = pix0 >> 12, wb = pix0 & 63;
        bool hin = (h >= 1 && h <= 62);
        for (int q = t; q < 1024; q += 256) {
            int c = q >> 3, w4l = (q & 7) * 4;
            int w4 = wb + w4l;
            float4 v = make_float4(0.f, 0.f, 0.f, 0.f);
            if (hin) {
                const float* xr = x + ((size_t)(b * CH + c)) * SPIN + (h - 1) * WIN;
                if (w4 == 0)       { f4a e = *(const f4a*)&xr[0];      v = make_float4(0.f, e[0], e[1], e[2]); }
                else if (w4 == 60) { f4a e = *(const f4a*)&xr[58];     v = make_float4(e[1], e[2], e[3], 0.f); }
                else               { f4a e = *(const f4a*)&xr[w4 - 1]; v = make_float4(e[0], e[1], e[2], e[3]); }
            }
            a16[(w4l + 0) * ASTRIDE + c] = (_Float16)v.x;
            a16[(w4l + 1) * ASTRIDE + c] = (_Float16)v.y;
            a16[(w4l + 2) * ASTRIDE + c] = (_Float16)v.z;
            a16[(w4l + 3) * ASTRIDE + c] = (_Float16)v.w;
        }
        __syncthreads();
        int lane = t & 63, ncol = lane & 15;
        int ntb = ((t >> 6) & 1) * 4;
        v4f acc[4];
        #pragma unroll
        for (int j = 0; j < 4; j++) {
            float bv = conv_b[(ntb + j) * 16 + ncol];
            acc[j] = (v4f){bv, bv, bv, bv};
        }
        mfma_loop8(a16, wp_conv, acc, t);
        __syncthreads();
        acc_to_a16_8(a16, acc, t);                       // a16 = y tile
        __syncthreads();
        {
            _Float16* dst = y16 + (size_t)pix0 * CH;
            for (int q = t; q < 512; q += 256)
                *(v8h*)&dst[q * 8] = *(const v8h*)&a16[(q >> 4) * ASTRIDE + (q & 15) * 8];
        }
        v4f acc2[4];
        #pragma unroll
        for (int j = 0; j < 4; j++) {
            float bv = in_b[(ntb + j) * 16 + ncol];
            acc2[j] = (v4f){bv, bv, bv, bv};
        }
        mfma_loop8(a16, wp_in, acc2, t);
        __syncthreads();
        acc_to_a16_8(a16, acc2, t);                      // a16 = x_proj tile
        __syncthreads();
        {
            _Float16* dst = xpad16 + (size_t)(((b * GP2) + h + 3) * GP2 + 3 + wb) * CH;
            for (int q = t; q < 512; q += 256)
                *(v8h*)&dst[q * 8] = *(const v8h*)&a16[(q >> 4) * ASTRIDE + (q & 15) * 8];
        }
    }
    gbar(bar + 1);

    // ========== phase 2: dw3x3 + LN + GELU + off/mask MFMA + taps, 32 px ====
    {
        _Float16* ylds = (_Float16*)smem;                // 48 rows x 34 cols, stride 35 (26880 B)
        int eff = xcd_swizzle(bid, 128);
        int pix0 = eff * 32;
        int h = (pix0 >> 6) & 63, b = pix0 >> 12, wb = pix0 & 63;
        for (int idx = t; idx < 1632; idx += 256) {
            int col = idx % 34;
            int rc  = idx / 34;
            int hh = h + (rc >> 4) - 1;
            int gw = wb - 1 + col;
            v8h v = (v8h)(_Float16)0;
            if ((unsigned)hh < 64u && (unsigned)gw < 64u)
                v = *(const v8h*)&y16[((size_t)((b * 64 + hh) * 64 + gw)) * CH + (rc & 15) * 8];
            *(v8h*)&ylds[(size_t)(rc * YSTRIDE + col) * 8] = v;
        }
        __syncthreads();
        int px = t >> 3, q8 = t & 7;
        float acc[16];
        #pragma unroll
        for (int cb = 0; cb < 4; cb++) *(float4*)&acc[cb * 4] = *(const float4*)&dw_b[q8 * 16 + cb * 4];
        #pragma unroll
        for (int r = 0; r < 3; r++) {
            #pragma unroll
            for (int kx = 0; kx < 3; kx++) {
                int col = px + kx;
                int tap = r * 3 + kx;
                #pragma unroll
                for (int cb = 0; cb < 2; cb++) {
                    v8h yv = *(const v8h*)&ylds[(size_t)((r * 16 + q8 * 2 + cb) * YSTRIDE + col) * 8];
                    float4 wa  = *(const float4*)&dwT[tap * 128 + q8 * 16 + cb * 8];
                    float4 wbv = *(const float4*)&dwT[tap * 128 + q8 * 16 + cb * 8 + 4];
                    acc[cb*8+0] += (float)yv[0] * wa.x;  acc[cb*8+1] += (float)yv[1] * wa.y;
                    acc[cb*8+2] += (float)yv[2] * wa.z;  acc[cb*8+3] += (float)yv[3] * wa.w;
                    acc[cb*8+4] += (float)yv[4] * wbv.x; acc[cb*8+5] += (float)yv[5] * wbv.y;
                    acc[cb*8+6] += (float)yv[6] * wbv.z; acc[cb*8+7] += (float)yv[7] * wbv.w;
                }
            }
        }
        float s = 0.f, ss = 0.f;
        #pragma unroll
        for (int j = 0; j < 16; j++) { s += acc[j]; ss += acc[j] * acc[j]; }
        s  += __shfl_xor(s, 1);  s  += __shfl_xor(s, 2);  s  += __shfl_xor(s, 4);
        ss += __shfl_xor(ss, 1); ss += __shfl_xor(ss, 2); ss += __shfl_xor(ss, 4);
        float mu = s * (1.f / 128.f);
        float var = ss * (1.f / 128.f) - mu * mu;
        float rstd = rsqrtf(var + 1e-5f);
        v8h dreg[2];
        #pragma unroll
        for (int cb = 0; cb < 2; cb++) {
            float4 ga = *(const float4*)&ln_g[q8 * 16 + cb * 8];
            float4 gb = *(const float4*)&ln_g[q8 * 16 + cb * 8 + 4];
            float4 ba = *(const float4*)&ln_b[q8 * 16 + cb * 8];
            float4 bb = *(const float4*)&ln_b[q8 * 16 + cb * 8 + 4];
            float gv[8] = {ga.x, ga.y, ga.z, ga.w, gb.x, gb.y, gb.z, gb.w};
            float bv[8] = {ba.x, ba.y, ba.z, ba.w, bb.x, bb.y, bb.z, bb.w};
            #pragma unroll
            for (int j = 0; j < 8; j++) {
                float xln = (acc[cb * 8 + j] - mu) * rstd * gv[j] + bv[j];
                float gel = 0.5f * xln * (1.f + erff(xln * 0.70710678118654752f));
                dreg[cb][j] = (_Float16)gel;
            }
        }
        __syncthreads();                                 // ylds dead
        _Float16* a16 = (_Float16*)smem;                 // 8704 B
        float* om = (float*)(smem + 8704);               // 32 x 112 f32
        #pragma unroll
        for (int cb = 0; cb < 2; cb++)
            *(v8h*)&a16[px * ASTRIDE + q8 * 16 + cb * 8] = dreg[cb];
        __syncthreads();
        int lane = t & 63, ncol = lane & 15;
        int ntb = ((t >> 6) & 1) * 4;
        v4f macc[4];
        #pragma unroll
        for (int j = 0; j < 4; j++) {
            int n = (ntb + j) * 16 + ncol;
            float bv = (n < 72) ? off_b[n] : (n < 108 ? mask_b[n - 72] : 0.f);
            macc[j] = (v4f){bv, bv, bv, bv};
        }
        mfma_loop8(a16, wp_om, macc, t);
        int m0 = ((t >> 6) >> 1) * 16 + ((lane >> 4) * 4);
        #pragma unroll
        for (int j = 0; j < 4; j++) {
            if (ntb + j < 7) {
                #pragma unroll
                for (int r = 0; r < 4; r++)
                    om[(m0 + r) * 112 + (ntb + j) * 16 + ncol] = macc[j][r];
            }
        }
        __syncthreads();
        {
            int job = t >> 1, half = t & 1;
            int pxs = job >> 2, gx = job & 3;
            const float* row = &om[pxs * 112];
            float lg[9];
            #pragma unroll
            for (int i = 0; i < 9; i++) lg[i] = row[72 + gx * 9 + i];
            float mx = lg[0];
            #pragma unroll
            for (int i = 1; i < 9; i++) mx = fmaxf(mx, lg[i]);
            float e[9], sum = 0.f;
            #pragma unroll
            for (int i = 0; i < 9; i++) { e[i] = expf(lg[i] - mx); sum += e[i]; }
            float inv = 1.f / sum;
            float* tm = tapmeta + ((size_t)(pix0 + pxs) * 36 + gx * 9) * 4;
            int pxg = wb + pxs;
            int pstart = half * 5;
            int pcount = half ? 4 : 5;
            #pragma unroll
            for (int ppi = 0; ppi < 5; ppi++) {
                if (ppi >= pcount) break;
                int p = pstart + ppi;
                int gp = gx * 9 + p;
                float offx = row[gp * 2];
                float offy = row[gp * 2 + 1];
                float m = e[p] * inv;
                float ix = (float)(pxg + (p / 3)) + offx;
                float iy = (float)(h + (p % 3)) + offy;
                ix = fminf(fmaxf(ix, -2.f), (float)(WP + 1));
                iy = fminf(fmaxf(iy, -2.f), (float)(HP + 1));
                float x0f = floorf(ix), y0f = floorf(iy);
                float fx = ix - x0f, fy = iy - y0f;
                int x0 = (int)x0f, y0 = (int)y0f;
                int off = ((y0 + 2) * GP2 + (x0 + 2)) * CH;
                float4 rec;
                rec.x = __int_as_float(off);
                rec.y = fx; rec.z = fy; rec.w = m;
                *(float4*)&tm[p * 4] = rec;
            }
        }
    }
    gbar(bar + 2);

    // ========== phase 3: gather (2 px/thread) + out_proj MFMA + NCHW ========
    {
        float* meta = (float*)smem;                      // [0, 18432)
        _Float16* a16 = (_Float16*)(smem + 18432);       // [18432, 27136)
        int eff = xcd_swizzle(bid, 128);
        int pix0 = eff * 32;
        int b = pix0 >> 12, h = (pix0 >> 6) & 63, wb = pix0 & 63;
        const float4* src = (const float4*)(tapmeta + (size_t)pix0 * 36 * 4);
        for (int i = t; i < 1152; i += 256) ((float4*)meta)[i] = src[i];
        __syncthreads();
        {
            int pp = t >> 4, s = t & 15;
            int ch = s * 8, g = s >> 2;
            const _Float16* base = xpad16 + (size_t)b * GP2 * GP2 * CH + ch;
            const float* tmA = &meta[(size_t)(pp * 36 + g * 9) * 4];
            const float* tmB = &meta[(size_t)((pp + 16) * 36 + g * 9) * 4];
            float accA[8], accB[8];
            #pragma unroll
            for (int j = 0; j < 8; j++) { accA[j] = 0.f; accB[j] = 0.f; }
            #pragma unroll
            for (int p = 0; p < 9; p++) {
                float4 rA = *(const float4*)&tmA[p * 4];
                float4 rB = *(const float4*)&tmB[p * 4];
                int oA = __float_as_int(rA.x), oB = __float_as_int(rB.x);
                float a11 = rA.y * rA.z, b11 = rB.y * rB.z;
                float a10 = rA.y - a11,  b10 = rB.y - b11;
                float a01 = rA.z - a11,  b01 = rB.z - b11;
                float a00 = 1.f - rA.y - rA.z + a11, b00 = 1.f - rB.y - rB.z + b11;
                a00 *= rA.w; a10 *= rA.w; a01 *= rA.w; a11 *= rA.w;
                b00 *= rB.w; b10 *= rB.w; b01 *= rB.w; b11 *= rB.w;
                v8h hA0 = *(const v8h*)&base[oA];
                v8h hA1 = *(const v8h*)&base[oA + CH];
                v8h hA2 = *(const v8h*)&base[oA + GP2 * CH];
                v8h hA3 = *(const v8h*)&base[oA + GP2 * CH + CH];
                v8h hB0 = *(const v8h*)&base[oB];
                v8h hB1 = *(const v8h*)&base[oB + CH];
                v8h hB2 = *(const v8h*)&base[oB + GP2 * CH];
                v8h hB3 = *(const v8h*)&base[oB + GP2 * CH + CH];
                #pragma unroll
                for (int j = 0; j < 8; j++) {
                    accA[j] += a00*(float)hA0[j] + a10*(float)hA1[j] + a01*(float)hA2[j] + a11*(float)hA3[j];
                    accB[j] += b00*(float)hB0[j] + b10*(float)hB1[j] + b01*(float)hB2[j] + b11*(float)hB3[j];
                }
            }
            v8h rA, rB;
            #pragma unroll
            for (int j = 0; j < 8; j++) { rA[j] = (_Float16)accA[j]; rB[j] = (_Float16)accB[j]; }
            *(v8h*)&a16[pp * ASTRIDE + ch] = rA;
            *(v8h*)&a16[(pp + 16) * ASTRIDE + ch] = rB;
        }
        __syncthreads();                                 // meta dead
        float* res = (float*)smem;                       // 128 x 40 f32
        int lane = t & 63, ncol = lane & 15;
        int ntb = ((t >> 6) & 1) * 4;
        v4f acc[4];
        #pragma unroll
        for (int j = 0; j < 4; j++) {
            float bv = out_b[(ntb + j) * 16 + ncol];
            acc[j] = (v4f){bv, bv, bv, bv};
        }
        mfma_loop8(a16, wp_out, acc, t);
        int m0 = ((t >> 6) >> 1) * 16 + ((lane >> 4) * 4);
        #pragma unroll
        for (int j = 0; j < 4; j++)
            #pragma unroll
            for (int r = 0; r < 4; r++)
                res[((ntb + j) * 16 + ncol) * 40 + (m0 + r)] = acc[j][r];   // [c][w]
        __syncthreads();
        for (int q = t; q < 1024; q += 256) {
            int cc = q >> 3, w4l = (q & 7) * 4;
            float4 o = *(const float4*)&res[cc * 40 + w4l];
            *(float4*)&out[(size_t)((b * CH + cc) * HH + h) * WWID + wb + w4l] = o;
        }
    }
}

extern "C" void kernel_launch(void* const* d_in, const int* in_sizes, int n_in,
                              void* d_out, int out_size, void* d_ws, size_t ws_size,
                              hipStream_t stream) {
    const float* x        = (const float*)d_in[0];
    const float* conv_w   = (const float*)d_in[1];
    const float* conv_b   = (const float*)d_in[2];
    const float* in_proj_w= (const float*)d_in[3];
    const float* in_proj_b= (const float*)d_in[4];
    const float* dw_w     = (const float*)d_in[5];
    const float* dw_b     = (const float*)d_in[6];
    const float* ln_g     = (const float*)d_in[7];
    const float* ln_b     = (const float*)d_in[8];
    const float* off_w    = (const float*)d_in[9];
    const float* off_b    = (const float*)d_in[10];
    const float* mask_w   = (const float*)d_in[11];
    const float* mask_b   = (const float*)d_in[12];
    const float* out_proj_w = (const float*)d_in[13];
    const float* out_proj_b = (const float*)d_in[14];
    float* out = (float*)d_out;

    float* ws = (float*)d_ws;
    const size_t O_BAR  = 0;
    const size_t O_WP   = 64;
    const size_t O_DWT  = O_WP + 32768;
    const size_t O_Y16  = O_DWT + 2048;
    const size_t O_XP16 = O_Y16 + 2097152;
    const size_t O_TM   = O_XP16 + 2508800;
    unsigned* bar    = (unsigned*)(ws + O_BAR);
    _Float16* wp     = (_Float16*)(ws + O_WP);
    float*    dwT    = ws + O_DWT;
    _Float16* y16    = (_Float16*)(ws + O_Y16);
    _Float16* xpad16 = (_Float16*)(ws + O_XP16);
    float*    tapmeta= ws + O_TM;

    hipMemsetAsync(bar, 0, 4 * sizeof(unsigned), stream);
    mega<<<NBLK, 256, 0, stream>>>(x, conv_w, conv_b, in_proj_w, in_proj_b,
                                   dw_w, dw_b, ln_g, ln_b, off_w, off_b,
                                   mask_w, mask_b, out_proj_w, out_proj_b,
                                   wp, dwT, y16, xpad16, tapmeta, bar, out);
}

// Round 17
// 211.228 us; speedup vs baseline: 3.5833x; 3.5833x over previous
//
#include <hip/hip_runtime.h>
#include <math.h>

#define BB 8
#define CH 128
#define HH 64
#define WWID 64
#define HIN 62
#define WIN 62
#define SPIN (HIN*WIN)      // 3844
#define HP 66
#define WP 66
#define GP2 70              // padded + 2-guard each side
#define NPIX (BB*HH*WWID)   // 32768
#define ASTRIDE 136         // LDS A-tile row stride in halfs
#define XPHALFS ((size_t)BB*GP2*GP2*CH)   // 5,017,600 halfs

typedef _Float16 v8h __attribute__((ext_vector_type(8)));
typedef float    v4f __attribute__((ext_vector_type(4)));
typedef float    f4a __attribute__((ext_vector_type(4), aligned(4)));

__device__ inline int xcd_swizzle(int bid, int nblk8) {
    return (bid & 7) * nblk8 + (bid >> 3);
}

// ---- P0: pack weights into MFMA B-frag order + dwT + zero xpad -------------
__global__ __launch_bounds__(256) void p0_pack(const float* __restrict__ conv_w,
                                               const float* __restrict__ in_proj_w,
                                               const float* __restrict__ off_w,
                                               const float* __restrict__ mask_w,
                                               const float* __restrict__ out_proj_w,
                                               const float* __restrict__ dw_w,
                                               _Float16* __restrict__ wp,
                                               float* __restrict__ dwT,
                                               _Float16* __restrict__ xpad16) {
    int t = threadIdx.x;
    int blk = blockIdx.x;
    if (blk >= 32) {                                 // blocks 32..63: zero xpad
        size_t nvec = XPHALFS / 8;
        for (size_t i = (size_t)(blk - 32) * 256 + t; i < nvec; i += 32 * 256)
            *(v8h*)&xpad16[i * 8] = (v8h)(_Float16)0;
        return;
    }
    if (blk == 31) {                                 // dwT[tap][c] transpose
        if (t < 128) {
            #pragma unroll
            for (int tap = 0; tap < 9; tap++) dwT[tap * 128 + t] = dw_w[t * 9 + tap];
        }
        return;
    }
    int tid = blk * 256 + t;                         // 0..7935
    int mat, base;
    if (tid < 2048)      { mat = 0; base = 0; }
    else if (tid < 4096) { mat = 1; base = 2048; }
    else if (tid < 5888) { mat = 2; base = 4096; }
    else                 { mat = 3; base = 5888; }
    int fi = tid - base;
    int nt = fi >> 8, rem = fi & 255, kc = rem >> 6, lane = rem & 63;
    int n = nt * 16 + (lane & 15);
    int kbase = kc * 32 + ((lane >> 4) & 3) * 8;
    _Float16* dst = wp + (size_t)tid * 8;
    #pragma unroll
    for (int j = 0; j < 8; j++) {
        int k = kbase + j;
        float v;
        if (mat == 0)      v = conv_w[n * CH + k];
        else if (mat == 1) v = in_proj_w[k * CH + n];
        else if (mat == 2) v = (n < 72) ? off_w[k * 72 + n]
                               : (n < 108 ? mask_w[k * 36 + (n - 72)] : 0.f);
        else               v = out_proj_w[k * CH + n];
        dst[j] = (_Float16)v;
    }
}

// ---- MFMA core: wave wv -> mt=wv>>1, ntb=(wv&1)*4 --------------------------
__device__ inline void mfma_loop8(const _Float16* __restrict__ a16,
                                  const _Float16* __restrict__ wp,
                                  v4f acc[4], int t) {
    int lane = t & 63;
    int wv = t >> 6;
    int mt = wv >> 1, ntb = (wv & 1) * 4;
    const _Float16* abase = a16 + (mt * 16 + (lane & 15)) * ASTRIDE + ((lane >> 4) * 8);
    #pragma unroll
    for (int kc = 0; kc < 4; kc++) {
        v8h av = *(const v8h*)(abase + kc * 32);
        #pragma unroll
        for (int j = 0; j < 4; j++) {
            v8h bv = *(const v8h*)(wp + ((size_t)((ntb + j) * 4 + kc) * 64 + lane) * 8);
            acc[j] = __builtin_amdgcn_mfma_f32_16x16x32_f16(av, bv, acc[j], 0, 0, 0);
        }
    }
}

__device__ inline void acc_to_a16_8(_Float16* a16, v4f acc[4], int t) {
    int lane = t & 63, ncol = lane & 15;
    int wv = t >> 6;
    int m0 = (wv >> 1) * 16 + ((lane >> 4) * 4);
    int ntb = (wv & 1) * 4;
    #pragma unroll
    for (int j = 0; j < 4; j++)
        #pragma unroll
        for (int r = 0; r < 4; r++)
            a16[(m0 + r) * ASTRIDE + (ntb + j) * 16 + ncol] = (_Float16)acc[j][r];
}

// ---- gA: fused conv1x1(pad=1) + in_proj; 32 px/block, 256 thr --------------
__global__ __launch_bounds__(256) void gA_conv_inproj(const float* __restrict__ x,
                                                      const _Float16* __restrict__ wp_conv,
                                                      const _Float16* __restrict__ wp_in,
                                                      const float* __restrict__ conv_b,
                                                      const float* __restrict__ in_b,
                                                      _Float16* __restrict__ y16,
                                                      _Float16* __restrict__ xpad16) {
    __shared__ _Float16 a16[32 * ASTRIDE];          // 8.7 KB
    int eff = xcd_swizzle(blockIdx.x, 128);
    int pix0 = eff * 32;
    int t = threadIdx.x;
    int h = (pix0 >> 6) & 63, b = pix0 >> 12, wb = pix0 & 63;
    bool hin = (h >= 1 && h <= 62);
    for (int q = t; q < 1024; q += 256) {
        int c = q >> 3, w4l = (q & 7) * 4;
        int w4 = wb + w4l;
        float4 v = make_float4(0.f, 0.f, 0.f, 0.f);
        if (hin) {
            const float* xr = x + ((size_t)(b * CH + c)) * SPIN + (h - 1) * WIN;
            if (w4 == 0)       { f4a e = *(const f4a*)&xr[0];      v = make_float4(0.f, e[0], e[1], e[2]); }
            else if (w4 == 60) { f4a e = *(const f4a*)&xr[58];     v = make_float4(e[1], e[2], e[3], 0.f); }
            else               { f4a e = *(const f4a*)&xr[w4 - 1]; v = make_float4(e[0], e[1], e[2], e[3]); }
        }
        a16[(w4l + 0) * ASTRIDE + c] = (_Float16)v.x;
        a16[(w4l + 1) * ASTRIDE + c] = (_Float16)v.y;
        a16[(w4l + 2) * ASTRIDE + c] = (_Float16)v.z;
        a16[(w4l + 3) * ASTRIDE + c] = (_Float16)v.w;
    }
    __syncthreads();
    int lane = t & 63, ncol = lane & 15;
    int ntb = ((t >> 6) & 1) * 4;
    v4f acc[4];
    #pragma unroll
    for (int j = 0; j < 4; j++) {
        float bv = conv_b[(ntb + j) * 16 + ncol];
        acc[j] = (v4f){bv, bv, bv, bv};
    }
    mfma_loop8(a16, wp_conv, acc, t);
    __syncthreads();
    acc_to_a16_8(a16, acc, t);                      // a16 = y tile
    __syncthreads();
    {
        _Float16* dst = y16 + (size_t)pix0 * CH;
        for (int q = t; q < 512; q += 256)
            *(v8h*)&dst[q * 8] = *(const v8h*)&a16[(q >> 4) * ASTRIDE + (q & 15) * 8];
    }
    v4f acc2[4];
    #pragma unroll
    for (int j = 0; j < 4; j++) {
        float bv = in_b[(ntb + j) * 16 + ncol];
        acc2[j] = (v4f){bv, bv, bv, bv};
    }
    mfma_loop8(a16, wp_in, acc2, t);
    __syncthreads();
    acc_to_a16_8(a16, acc2, t);                     // a16 = x_proj tile
    __syncthreads();
    {
        _Float16* dst = xpad16 + (size_t)(((b * GP2) + h + 3) * GP2 + 3 + wb) * CH;
        for (int q = t; q < 512; q += 256)
            *(v8h*)&dst[q * 8] = *(const v8h*)&a16[(q >> 4) * ASTRIDE + (q & 15) * 8];
    }
}

// ---- gF: dw3x3+LN+GELU+off/mask MFMA+softmax+taps+GATHER+out_proj+store ----
// 512 thr, one 64-px row per block, 512 blocks (XCD-swizzled: batch per XCD).
__global__ __launch_bounds__(512) void gF_mega(const _Float16* __restrict__ y16,
                                               const _Float16* __restrict__ xpad16,
                                               const _Float16* __restrict__ wp_om,
                                               const _Float16* __restrict__ wp_out,
                                               const float* __restrict__ dwT,
                                               const float* __restrict__ dw_b,
                                               const float* __restrict__ ln_g,
                                               const float* __restrict__ ln_b,
                                               const float* __restrict__ off_b,
                                               const float* __restrict__ mask_b,
                                               const float* __restrict__ out_b,
                                               float* __restrict__ out) {
    __shared__ char smem[49920];
    _Float16* ylds = (_Float16*)smem;               // v8h idx: (r*16+c8)*65 + w
    int t = threadIdx.x;
    int eff = xcd_swizzle(blockIdx.x, 64);
    int pix0 = eff * 64;
    int h = (pix0 >> 6) & 63, b = pix0 >> 12;
    if (h == 0 || h == 63) {
        for (int i = t; i < 3120; i += 512) *(v8h*)&ylds[i * 8] = (v8h)(_Float16)0;
        __syncthreads();
    }
    for (int idx = t; idx < 3072; idx += 512) {
        int r = idx >> 10, w = (idx >> 4) & 63, c8 = idx & 15;
        int hh = h + r - 1;
        if (hh >= 0 && hh <= 63) {
            v8h v = *(const v8h*)&y16[(size_t)(((b * 64 + hh) * 64 + w) * CH) + c8 * 8];
            *(v8h*)&ylds[(size_t)((r * 16 + c8) * 65 + w) * 8] = v;
        }
    }
    __syncthreads();
    int px = t >> 3, q8 = t & 7;
    float acc[16];
    #pragma unroll
    for (int cb = 0; cb < 4; cb++) *(float4*)&acc[cb * 4] = *(const float4*)&dw_b[q8 * 16 + cb * 4];
    #pragma unroll
    for (int r = 0; r < 3; r++) {
        #pragma unroll
        for (int kx = 0; kx < 3; kx++) {
            int wq = px + kx - 1;
            bool valid = (wq >= 0 && wq <= 63);
            int wpc = min(max(wq, 0), 63);
            int tap = r * 3 + kx;
            if (valid) {
                #pragma unroll
                for (int cb = 0; cb < 2; cb++) {
                    v8h yv = *(const v8h*)&ylds[(size_t)((r * 16 + q8 * 2 + cb) * 65 + wpc) * 8];
                    float4 wa  = *(const float4*)&dwT[tap * 128 + q8 * 16 + cb * 8];
                    float4 wbv = *(const float4*)&dwT[tap * 128 + q8 * 16 + cb * 8 + 4];
                    acc[cb*8+0] += (float)yv[0] * wa.x;  acc[cb*8+1] += (float)yv[1] * wa.y;
                    acc[cb*8+2] += (float)yv[2] * wa.z;  acc[cb*8+3] += (float)yv[3] * wa.w;
                    acc[cb*8+4] += (float)yv[4] * wbv.x; acc[cb*8+5] += (float)yv[5] * wbv.y;
                    acc[cb*8+6] += (float)yv[6] * wbv.z; acc[cb*8+7] += (float)yv[7] * wbv.w;
                }
            }
        }
    }
    float s = 0.f, ss = 0.f;
    #pragma unroll
    for (int j = 0; j < 16; j++) { s += acc[j]; ss += acc[j] * acc[j]; }
    s  += __shfl_xor(s, 1);  s  += __shfl_xor(s, 2);  s  += __shfl_xor(s, 4);
    ss += __shfl_xor(ss, 1); ss += __shfl_xor(ss, 2); ss += __shfl_xor(ss, 4);
    float mu = s * (1.f / 128.f);
    float var = ss * (1.f / 128.f) - mu * mu;
    float rstd = rsqrtf(var + 1e-5f);
    v8h dreg[2];
    #pragma unroll
    for (int cb = 0; cb < 2; cb++) {
        float4 ga = *(const float4*)&ln_g[q8 * 16 + cb * 8];
        float4 gb = *(const float4*)&ln_g[q8 * 16 + cb * 8 + 4];
        float4 ba = *(const float4*)&ln_b[q8 * 16 + cb * 8];
        float4 bb = *(const float4*)&ln_b[q8 * 16 + cb * 8 + 4];
        float gv[8] = {ga.x, ga.y, ga.z, ga.w, gb.x, gb.y, gb.z, gb.w};
        float bv[8] = {ba.x, ba.y, ba.z, ba.w, bb.x, bb.y, bb.z, bb.w};
        #pragma unroll
        for (int j = 0; j < 8; j++) {
            float xln = (acc[cb * 8 + j] - mu) * rstd * gv[j] + bv[j];
            float gel = 0.5f * xln * (1.f + erff(xln * 0.70710678118654752f));
            dreg[cb][j] = (_Float16)gel;
        }
    }
    __syncthreads();                                // ylds dead
    _Float16* a16 = (_Float16*)smem;                // [0, 17408)
    float* om = (float*)(smem + 17408);             // [17408, 46080): 64 x 112 f32
    #pragma unroll
    for (int cb = 0; cb < 2; cb++)
        *(v8h*)&a16[px * ASTRIDE + q8 * 16 + cb * 8] = dreg[cb];
    __syncthreads();
    int lane = t & 63, ncol = lane & 15;
    int ntb = ((t >> 6) & 1) * 4;
    {
        v4f macc[4];
        #pragma unroll
        for (int j = 0; j < 4; j++) {
            int n = (ntb + j) * 16 + ncol;
            float bv = (n < 72) ? off_b[n] : (n < 108 ? mask_b[n - 72] : 0.f);
            macc[j] = (v4f){bv, bv, bv, bv};
        }
        mfma_loop8(a16, wp_om, macc, t);
        int m0 = ((t >> 6) >> 1) * 16 + ((lane >> 4) * 4);
        #pragma unroll
        for (int j = 0; j < 4; j++) {
            if (ntb + j < 7) {
                #pragma unroll
                for (int r = 0; r < 4; r++)
                    om[(m0 + r) * 112 + (ntb + j) * 16 + ncol] = macc[j][r];
            }
        }
    }
    __syncthreads();
    // ---- per-thread softmax + taps + gather: px = t>>3, s = t&7 -> 16 ch ---
    {
        int s8 = t & 7;
        int ch = s8 * 16, g = s8 >> 1;
        g = s8 >> 1;                                 // 8 slots: 2 per group? NO:
        g = s8 >> 1;                                 // groups 0..3 need s>>1
        // slots s8 0..7 -> ch 0..112; group = ch/32 = s8>>1
        const float* row = &om[px * 112];
        float lg[9];
        #pragma unroll
        for (int i = 0; i < 9; i++) lg[i] = row[72 + g * 9 + i];
        float mx = lg[0];
        #pragma unroll
        for (int i = 1; i < 9; i++) mx = fmaxf(mx, lg[i]);
        float e[9], sum = 0.f;
        #pragma unroll
        for (int i = 0; i < 9; i++) { e[i] = expf(lg[i] - mx); sum += e[i]; }
        float inv = 1.f / sum;
        const _Float16* base = xpad16 + (size_t)b * GP2 * GP2 * CH + ch;
        float gacc[16];
        #pragma unroll
        for (int j = 0; j < 16; j++) gacc[j] = 0.f;
        #pragma unroll
        for (int p = 0; p < 9; p++) {
            float offx = row[(g * 9 + p) * 2];
            float offy = row[(g * 9 + p) * 2 + 1];
            float m = e[p] * inv;
            float ix = (float)(px + (p / 3)) + offx;
            float iy = (float)(h + (p % 3)) + offy;
            ix = fminf(fmaxf(ix, -2.f), (float)(WP + 1));
            iy = fminf(fmaxf(iy, -2.f), (float)(HP + 1));
            float x0f = floorf(ix), y0f = floorf(iy);
            float fx = ix - x0f, fy = iy - y0f;
            int x0 = (int)x0f, y0 = (int)y0f;
            int off = ((y0 + 2) * GP2 + (x0 + 2)) * CH;
            float w11 = fx * fy;
            float w10 = fx - w11;
            float w01 = fy - w11;
            float w00 = 1.f - fx - fy + w11;
            w00 *= m; w10 *= m; w01 *= m; w11 *= m;
            v8h c0a = *(const v8h*)&base[off];
            v8h c0b = *(const v8h*)&base[off + 8];
            v8h c1a = *(const v8h*)&base[off + CH];
            v8h c1b = *(const v8h*)&base[off + CH + 8];
            v8h c2a = *(const v8h*)&base[off + GP2 * CH];
            v8h c2b = *(const v8h*)&base[off + GP2 * CH + 8];
            v8h c3a = *(const v8h*)&base[off + GP2 * CH + CH];
            v8h c3b = *(const v8h*)&base[off + GP2 * CH + CH + 8];
            #pragma unroll
            for (int j = 0; j < 8; j++) {
                gacc[j]     += w00*(float)c0a[j] + w10*(float)c1a[j] + w01*(float)c2a[j] + w11*(float)c3a[j];
                gacc[j + 8] += w00*(float)c0b[j] + w10*(float)c1b[j] + w01*(float)c2b[j] + w11*(float)c3b[j];
            }
        }
        __syncthreads();                             // all om reads complete
        v8h r0, r1;
        #pragma unroll
        for (int j = 0; j < 8; j++) { r0[j] = (_Float16)gacc[j]; r1[j] = (_Float16)gacc[j + 8]; }
        *(v8h*)&a16[px * ASTRIDE + ch]     = r0;     // a16 = core tile
        *(v8h*)&a16[px * ASTRIDE + ch + 8] = r1;
    }
    __syncthreads();
    // ---- out_proj MFMA + NCHW store ----
    {
        v4f oacc[4];
        #pragma unroll
        for (int j = 0; j < 4; j++) {
            float bv = out_b[(ntb + j) * 16 + ncol];
            oacc[j] = (v4f){bv, bv, bv, bv};
        }
        mfma_loop8(a16, wp_out, oacc, t);
        __syncthreads();                             // a16 reads done
        float* res = (float*)smem;                   // 128 x 68 f32 = 34816 B
        int m0 = ((t >> 6) >> 1) * 16 + ((lane >> 4) * 4);
        #pragma unroll
        for (int j = 0; j < 4; j++)
            #pragma unroll
            for (int r = 0; r < 4; r++)
                res[((ntb + j) * 16 + ncol) * 68 + (m0 + r)] = oacc[j][r];
        __syncthreads();
        for (int q = t; q < 2048; q += 512) {
            int cc = q >> 4, w4 = (q & 15) * 4;
            float4 o = *(const float4*)&res[cc * 68 + w4];
            *(float4*)&out[(size_t)((b * CH + cc) * HH + h) * WWID + w4] = o;
        }
    }
}

extern "C" void kernel_launch(void* const* d_in, const int* in_sizes, int n_in,
                              void* d_out, int out_size, void* d_ws, size_t ws_size,
                              hipStream_t stream) {
    const float* x        = (const float*)d_in[0];
    const float* conv_w   = (const float*)d_in[1];
    const float* conv_b   = (const float*)d_in[2];
    const float* in_proj_w= (const float*)d_in[3];
    const float* in_proj_b= (const float*)d_in[4];
    const float* dw_w     = (const float*)d_in[5];
    const float* dw_b     = (const float*)d_in[6];
    const float* ln_g     = (const float*)d_in[7];
    const float* ln_b     = (const float*)d_in[8];
    const float* off_w    = (const float*)d_in[9];
    const float* off_b    = (const float*)d_in[10];
    const float* mask_w   = (const float*)d_in[11];
    const float* mask_b   = (const float*)d_in[12];
    const float* out_proj_w = (const float*)d_in[13];
    const float* out_proj_b = (const float*)d_in[14];
    float* out = (float*)d_out;

    float* ws = (float*)d_ws;
    // float-offsets: wp | dwT | y16 | xpad16(70x70 guard)
    const size_t O_WP   = 0;
    const size_t O_DWT  = 32768;
    const size_t O_Y16  = 34816;                    // 2,097,152 floats (halfs)
    const size_t O_XP16 = O_Y16 + 2097152;          // 2,508,800 floats
    _Float16* wp     = (_Float16*)(ws + O_WP);
    float*    dwT    = ws + O_DWT;
    _Float16* y16    = (_Float16*)(ws + O_Y16);
    _Float16* xpad16 = (_Float16*)(ws + O_XP16);

    _Float16* wp_conv = wp;
    _Float16* wp_in   = wp + (size_t)2048 * 8;
    _Float16* wp_om   = wp + (size_t)4096 * 8;
    _Float16* wp_out  = wp + (size_t)5888 * 8;

    p0_pack<<<64, 256, 0, stream>>>(conv_w, in_proj_w, off_w, mask_w, out_proj_w, dw_w, wp, dwT, xpad16);
    gA_conv_inproj<<<NPIX / 32, 256, 0, stream>>>(x, wp_conv, wp_in, conv_b, in_proj_b, y16, xpad16);
    gF_mega<<<NPIX / 64, 512, 0, stream>>>(y16, xpad16, wp_om, wp_out, dwT, dw_b,
                                           ln_g, ln_b, off_b, mask_b, out_proj_b, out);
}

// Round 18
// 152.691 us; speedup vs baseline: 4.9571x; 1.3834x over previous
//
#include <hip/hip_runtime.h>
#include <math.h>

#define BB 8
#define CH 128
#define HH 64
#define WWID 64
#define HIN 62
#define WIN 62
#define SPIN (HIN*WIN)      // 3844
#define HP 66
#define WP 66
#define GP2 70              // padded + 2-guard each side
#define NPIX (BB*HH*WWID)   // 32768
#define ASTRIDE 136         // LDS A-tile row stride in halfs
#define XPHALFS ((size_t)BB*GP2*GP2*CH)   // 5,017,600 halfs

typedef _Float16 v8h __attribute__((ext_vector_type(8)));
typedef float    v4f __attribute__((ext_vector_type(4)));
typedef float    f4a __attribute__((ext_vector_type(4), aligned(4)));

__device__ inline int xcd_swizzle(int bid, int nblk8) {
    return (bid & 7) * nblk8 + (bid >> 3);
}

// ---- P0: pack weights into MFMA B-frag order + dwT + zero xpad -------------
__global__ __launch_bounds__(256) void p0_pack(const float* __restrict__ conv_w,
                                               const float* __restrict__ in_proj_w,
                                               const float* __restrict__ off_w,
                                               const float* __restrict__ mask_w,
                                               const float* __restrict__ out_proj_w,
                                               const float* __restrict__ dw_w,
                                               _Float16* __restrict__ wp,
                                               float* __restrict__ dwT,
                                               _Float16* __restrict__ xpad16) {
    int t = threadIdx.x;
    int blk = blockIdx.x;
    if (blk >= 32) {                                 // blocks 32..63: zero xpad
        size_t nvec = XPHALFS / 8;
        for (size_t i = (size_t)(blk - 32) * 256 + t; i < nvec; i += 32 * 256)
            *(v8h*)&xpad16[i * 8] = (v8h)(_Float16)0;
        return;
    }
    if (blk == 31) {                                 // dwT[tap][c] transpose
        if (t < 128) {
            #pragma unroll
            for (int tap = 0; tap < 9; tap++) dwT[tap * 128 + t] = dw_w[t * 9 + tap];
        }
        return;
    }
    int tid = blk * 256 + t;                         // 0..7935
    int mat, base;
    if (tid < 2048)      { mat = 0; base = 0; }
    else if (tid < 4096) { mat = 1; base = 2048; }
    else if (tid < 5888) { mat = 2; base = 4096; }
    else                 { mat = 3; base = 5888; }
    int fi = tid - base;
    int nt = fi >> 8, rem = fi & 255, kc = rem >> 6, lane = rem & 63;
    int n = nt * 16 + (lane & 15);
    int kbase = kc * 32 + ((lane >> 4) & 3) * 8;
    _Float16* dst = wp + (size_t)tid * 8;
    #pragma unroll
    for (int j = 0; j < 8; j++) {
        int k = kbase + j;
        float v;
        if (mat == 0)      v = conv_w[n * CH + k];
        else if (mat == 1) v = in_proj_w[k * CH + n];
        else if (mat == 2) v = (n < 72) ? off_w[k * 72 + n]
                               : (n < 108 ? mask_w[k * 36 + (n - 72)] : 0.f);
        else               v = out_proj_w[k * CH + n];
        dst[j] = (_Float16)v;
    }
}

// ---- MFMA core: wave wv -> mt=wv>>1, ntb=(wv&1)*4 --------------------------
__device__ inline void mfma_loop8(const _Float16* __restrict__ a16,
                                  const _Float16* __restrict__ wp,
                                  v4f acc[4], int t) {
    int lane = t & 63;
    int wv = t >> 6;
    int mt = wv >> 1, ntb = (wv & 1) * 4;
    const _Float16* abase = a16 + (mt * 16 + (lane & 15)) * ASTRIDE + ((lane >> 4) * 8);
    #pragma unroll
    for (int kc = 0; kc < 4; kc++) {
        v8h av = *(const v8h*)(abase + kc * 32);
        #pragma unroll
        for (int j = 0; j < 4; j++) {
            v8h bv = *(const v8h*)(wp + ((size_t)((ntb + j) * 4 + kc) * 64 + lane) * 8);
            acc[j] = __builtin_amdgcn_mfma_f32_16x16x32_f16(av, bv, acc[j], 0, 0, 0);
        }
    }
}

__device__ inline void acc_to_a16_8(_Float16* a16, v4f acc[4], int t) {
    int lane = t & 63, ncol = lane & 15;
    int wv = t >> 6;
    int m0 = (wv >> 1) * 16 + ((lane >> 4) * 4);
    int ntb = (wv & 1) * 4;
    #pragma unroll
    for (int j = 0; j < 4; j++)
        #pragma unroll
        for (int r = 0; r < 4; r++)
            a16[(m0 + r) * ASTRIDE + (ntb + j) * 16 + ncol] = (_Float16)acc[j][r];
}

// ---- gA: fused conv1x1(pad=1) + in_proj; 32 px/block, 256 thr --------------
__global__ __launch_bounds__(256) void gA_conv_inproj(const float* __restrict__ x,
                                                      const _Float16* __restrict__ wp_conv,
                                                      const _Float16* __restrict__ wp_in,
                                                      const float* __restrict__ conv_b,
                                                      const float* __restrict__ in_b,
                                                      _Float16* __restrict__ y16,
                                                      _Float16* __restrict__ xpad16) {
    __shared__ _Float16 a16[32 * ASTRIDE];          // 8.7 KB
    int eff = xcd_swizzle(blockIdx.x, 128);
    int pix0 = eff * 32;
    int t = threadIdx.x;
    int h = (pix0 >> 6) & 63, b = pix0 >> 12, wb = pix0 & 63;
    bool hin = (h >= 1 && h <= 62);
    for (int q = t; q < 1024; q += 256) {
        int c = q >> 3, w4l = (q & 7) * 4;
        int w4 = wb + w4l;
        float4 v = make_float4(0.f, 0.f, 0.f, 0.f);
        if (hin) {
            const float* xr = x + ((size_t)(b * CH + c)) * SPIN + (h - 1) * WIN;
            if (w4 == 0)       { f4a e = *(const f4a*)&xr[0];      v = make_float4(0.f, e[0], e[1], e[2]); }
            else if (w4 == 60) { f4a e = *(const f4a*)&xr[58];     v = make_float4(e[1], e[2], e[3], 0.f); }
            else               { f4a e = *(const f4a*)&xr[w4 - 1]; v = make_float4(e[0], e[1], e[2], e[3]); }
        }
        a16[(w4l + 0) * ASTRIDE + c] = (_Float16)v.x;
        a16[(w4l + 1) * ASTRIDE + c] = (_Float16)v.y;
        a16[(w4l + 2) * ASTRIDE + c] = (_Float16)v.z;
        a16[(w4l + 3) * ASTRIDE + c] = (_Float16)v.w;
    }
    __syncthreads();
    int lane = t & 63, ncol = lane & 15;
    int ntb = ((t >> 6) & 1) * 4;
    v4f acc[4];
    #pragma unroll
    for (int j = 0; j < 4; j++) {
        float bv = conv_b[(ntb + j) * 16 + ncol];
        acc[j] = (v4f){bv, bv, bv, bv};
    }
    mfma_loop8(a16, wp_conv, acc, t);
    __syncthreads();
    acc_to_a16_8(a16, acc, t);                      // a16 = y tile
    __syncthreads();
    {
        _Float16* dst = y16 + (size_t)pix0 * CH;
        for (int q = t; q < 512; q += 256)
            *(v8h*)&dst[q * 8] = *(const v8h*)&a16[(q >> 4) * ASTRIDE + (q & 15) * 8];
    }
    v4f acc2[4];
    #pragma unroll
    for (int j = 0; j < 4; j++) {
        float bv = in_b[(ntb + j) * 16 + ncol];
        acc2[j] = (v4f){bv, bv, bv, bv};
    }
    mfma_loop8(a16, wp_in, acc2, t);
    __syncthreads();
    acc_to_a16_8(a16, acc2, t);                     // a16 = x_proj tile
    __syncthreads();
    {
        _Float16* dst = xpad16 + (size_t)(((b * GP2) + h + 3) * GP2 + 3 + wb) * CH;
        for (int q = t; q < 512; q += 256)
            *(v8h*)&dst[q * 8] = *(const v8h*)&a16[(q >> 4) * ASTRIDE + (q & 15) * 8];
    }
}

// ---- gF: dw3x3+LN+GELU+off/mask MFMA+softmax+taps+GATHER+out_proj+store ----
// 512 thr, one 64-px row/block. __launch_bounds__(512,2): VGPR cap 256 -> no
// scratch spill (R17's 128-cap spilled ~190 MB of scratch traffic).
__global__ __launch_bounds__(512, 2) void gF_mega(const _Float16* __restrict__ y16,
                                                  const _Float16* __restrict__ xpad16,
                                                  const _Float16* __restrict__ wp_om,
                                                  const _Float16* __restrict__ wp_out,
                                                  const float* __restrict__ dwT,
                                                  const float* __restrict__ dw_b,
                                                  const float* __restrict__ ln_g,
                                                  const float* __restrict__ ln_b,
                                                  const float* __restrict__ off_b,
                                                  const float* __restrict__ mask_b,
                                                  const float* __restrict__ out_b,
                                                  float* __restrict__ out) {
    __shared__ char smem[49920];
    _Float16* ylds = (_Float16*)smem;               // v8h idx: (r*16+c8)*65 + w
    int t = threadIdx.x;
    int eff = xcd_swizzle(blockIdx.x, 64);
    int pix0 = eff * 64;
    int h = (pix0 >> 6) & 63, b = pix0 >> 12;
    if (h == 0 || h == 63) {
        for (int i = t; i < 3120; i += 512) *(v8h*)&ylds[i * 8] = (v8h)(_Float16)0;
        __syncthreads();
    }
    for (int idx = t; idx < 3072; idx += 512) {
        int r = idx >> 10, w = (idx >> 4) & 63, c8 = idx & 15;
        int hh = h + r - 1;
        if (hh >= 0 && hh <= 63) {
            v8h v = *(const v8h*)&y16[(size_t)(((b * 64 + hh) * 64 + w) * CH) + c8 * 8];
            *(v8h*)&ylds[(size_t)((r * 16 + c8) * 65 + w) * 8] = v;
        }
    }
    __syncthreads();
    int px = t >> 3, q8 = t & 7;
    float acc[16];
    #pragma unroll
    for (int cb = 0; cb < 4; cb++) *(float4*)&acc[cb * 4] = *(const float4*)&dw_b[q8 * 16 + cb * 4];
    #pragma unroll
    for (int r = 0; r < 3; r++) {
        #pragma unroll
        for (int kx = 0; kx < 3; kx++) {
            int wq = px + kx - 1;
            bool valid = (wq >= 0 && wq <= 63);
            int wpc = min(max(wq, 0), 63);
            int tap = r * 3 + kx;
            if (valid) {
                #pragma unroll
                for (int cb = 0; cb < 2; cb++) {
                    v8h yv = *(const v8h*)&ylds[(size_t)((r * 16 + q8 * 2 + cb) * 65 + wpc) * 8];
                    float4 wa  = *(const float4*)&dwT[tap * 128 + q8 * 16 + cb * 8];
                    float4 wbv = *(const float4*)&dwT[tap * 128 + q8 * 16 + cb * 8 + 4];
                    acc[cb*8+0] += (float)yv[0] * wa.x;  acc[cb*8+1] += (float)yv[1] * wa.y;
                    acc[cb*8+2] += (float)yv[2] * wa.z;  acc[cb*8+3] += (float)yv[3] * wa.w;
                    acc[cb*8+4] += (float)yv[4] * wbv.x; acc[cb*8+5] += (float)yv[5] * wbv.y;
                    acc[cb*8+6] += (float)yv[6] * wbv.z; acc[cb*8+7] += (float)yv[7] * wbv.w;
                }
            }
        }
    }
    float s = 0.f, ss = 0.f;
    #pragma unroll
    for (int j = 0; j < 16; j++) { s += acc[j]; ss += acc[j] * acc[j]; }
    s  += __shfl_xor(s, 1);  s  += __shfl_xor(s, 2);  s  += __shfl_xor(s, 4);
    ss += __shfl_xor(ss, 1); ss += __shfl_xor(ss, 2); ss += __shfl_xor(ss, 4);
    float mu = s * (1.f / 128.f);
    float var = ss * (1.f / 128.f) - mu * mu;
    float rstd = rsqrtf(var + 1e-5f);
    v8h dreg[2];
    #pragma unroll
    for (int cb = 0; cb < 2; cb++) {
        float4 ga = *(const float4*)&ln_g[q8 * 16 + cb * 8];
        float4 gb = *(const float4*)&ln_g[q8 * 16 + cb * 8 + 4];
        float4 ba = *(const float4*)&ln_b[q8 * 16 + cb * 8];
        float4 bb = *(const float4*)&ln_b[q8 * 16 + cb * 8 + 4];
        float gv[8] = {ga.x, ga.y, ga.z, ga.w, gb.x, gb.y, gb.z, gb.w};
        float bv[8] = {ba.x, ba.y, ba.z, ba.w, bb.x, bb.y, bb.z, bb.w};
        #pragma unroll
        for (int j = 0; j < 8; j++) {
            float xln = (acc[cb * 8 + j] - mu) * rstd * gv[j] + bv[j];
            float gel = 0.5f * xln * (1.f + erff(xln * 0.70710678118654752f));
            dreg[cb][j] = (_Float16)gel;
        }
    }
    __syncthreads();                                // ylds dead
    _Float16* a16 = (_Float16*)smem;                // [0, 17408)
    float* om = (float*)(smem + 17408);             // [17408, 46080): 64 x 112 f32
    #pragma unroll
    for (int cb = 0; cb < 2; cb++)
        *(v8h*)&a16[px * ASTRIDE + q8 * 16 + cb * 8] = dreg[cb];
    __syncthreads();
    int lane = t & 63, ncol = lane & 15;
    int ntb = ((t >> 6) & 1) * 4;
    {
        v4f macc[4];
        #pragma unroll
        for (int j = 0; j < 4; j++) {
            int n = (ntb + j) * 16 + ncol;
            float bv = (n < 72) ? off_b[n] : (n < 108 ? mask_b[n - 72] : 0.f);
            macc[j] = (v4f){bv, bv, bv, bv};
        }
        mfma_loop8(a16, wp_om, macc, t);
        int m0 = ((t >> 6) >> 1) * 16 + ((lane >> 4) * 4);
        #pragma unroll
        for (int j = 0; j < 4; j++) {
            if (ntb + j < 7) {
                #pragma unroll
                for (int r = 0; r < 4; r++)
                    om[(m0 + r) * 112 + (ntb + j) * 16 + ncol] = macc[j][r];
            }
        }
    }
    __syncthreads();
    // ---- softmax + taps + gather: px = t>>3, slot s8 = t&7 -> 16 ch --------
    // Two sequential 8-ch passes to halve live-register pressure (spill fix).
    {
        int s8 = t & 7;
        int ch = s8 * 16, g = s8 >> 1;              // group = ch/32
        const float* row = &om[px * 112];
        float lg[9];
        #pragma unroll
        for (int i = 0; i < 9; i++) lg[i] = row[72 + g * 9 + i];
        float mx = lg[0];
        #pragma unroll
        for (int i = 1; i < 9; i++) mx = fmaxf(mx, lg[i]);
        float e[9], sum = 0.f;
        #pragma unroll
        for (int i = 0; i < 9; i++) { e[i] = expf(lg[i] - mx); sum += e[i]; }
        float inv = 1.f / sum;
        #pragma unroll
        for (int half = 0; half < 2; half++) {
            const _Float16* base = xpad16 + (size_t)b * GP2 * GP2 * CH + ch + half * 8;
            float gacc[8];
            #pragma unroll
            for (int j = 0; j < 8; j++) gacc[j] = 0.f;
            #pragma unroll
            for (int p = 0; p < 9; p++) {
                float offx = row[(g * 9 + p) * 2];
                float offy = row[(g * 9 + p) * 2 + 1];
                float m = e[p] * inv;
                float ix = (float)(px + (p / 3)) + offx;
                float iy = (float)(h + (p % 3)) + offy;
                ix = fminf(fmaxf(ix, -2.f), (float)(WP + 1));
                iy = fminf(fmaxf(iy, -2.f), (float)(HP + 1));
                float x0f = floorf(ix), y0f = floorf(iy);
                float fx = ix - x0f, fy = iy - y0f;
                int x0 = (int)x0f, y0 = (int)y0f;
                int off = ((y0 + 2) * GP2 + (x0 + 2)) * CH;
                float w11 = fx * fy;
                float w10 = fx - w11;
                float w01 = fy - w11;
                float w00 = 1.f - fx - fy + w11;
                w00 *= m; w10 *= m; w01 *= m; w11 *= m;
                v8h h0 = *(const v8h*)&base[off];
                v8h h1 = *(const v8h*)&base[off + CH];
                v8h h2 = *(const v8h*)&base[off + GP2 * CH];
                v8h h3 = *(const v8h*)&base[off + GP2 * CH + CH];
                #pragma unroll
                for (int j = 0; j < 8; j++)
                    gacc[j] += w00*(float)h0[j] + w10*(float)h1[j] + w01*(float)h2[j] + w11*(float)h3[j];
            }
            v8h r0;
            #pragma unroll
            for (int j = 0; j < 8; j++) r0[j] = (_Float16)gacc[j];
            *(v8h*)&a16[px * ASTRIDE + ch + half * 8] = r0;   // a16 = core tile
        }
    }
    __syncthreads();
    // ---- out_proj MFMA + NCHW store ----
    {
        v4f oacc[4];
        #pragma unroll
        for (int j = 0; j < 4; j++) {
            float bv = out_b[(ntb + j) * 16 + ncol];
            oacc[j] = (v4f){bv, bv, bv, bv};
        }
        mfma_loop8(a16, wp_out, oacc, t);
        __syncthreads();                             // a16 reads done
        float* res = (float*)smem;                   // 128 x 68 f32 = 34816 B
        int m0 = ((t >> 6) >> 1) * 16 + ((lane >> 4) * 4);
        #pragma unroll
        for (int j = 0; j < 4; j++)
            #pragma unroll
            for (int r = 0; r < 4; r++)
                res[((ntb + j) * 16 + ncol) * 68 + (m0 + r)] = oacc[j][r];
        __syncthreads();
        for (int q = t; q < 2048; q += 512) {
            int cc = q >> 4, w4 = (q & 15) * 4;
            float4 o = *(const float4*)&res[cc * 68 + w4];
            *(float4*)&out[(size_t)((b * CH + cc) * HH + h) * WWID + w4] = o;
        }
    }
}

extern "C" void kernel_launch(void* const* d_in, const int* in_sizes, int n_in,
                              void* d_out, int out_size, void* d_ws, size_t ws_size,
                              hipStream_t stream) {
    const float* x        = (const float*)d_in[0];
    const float* conv_w   = (const float*)d_in[1];
    const float* conv_b   = (const float*)d_in[2];
    const float* in_proj_w= (const float*)d_in[3];
    const float* in_proj_b= (const float*)d_in[4];
    const float* dw_w     = (const float*)d_in[5];
    const float* dw_b     = (const float*)d_in[6];
    const float* ln_g     = (const float*)d_in[7];
    const float* ln_b     = (const float*)d_in[8];
    const float* off_w    = (const float*)d_in[9];
    const float* off_b    = (const float*)d_in[10];
    const float* mask_w   = (const float*)d_in[11];
    const float* mask_b   = (const float*)d_in[12];
    const float* out_proj_w = (const float*)d_in[13];
    const float* out_proj_b = (const float*)d_in[14];
    float* out = (float*)d_out;

    float* ws = (float*)d_ws;
    const size_t O_WP   = 0;
    const size_t O_DWT  = 32768;
    const size_t O_Y16  = 34816;
    const size_t O_XP16 = O_Y16 + 2097152;
    _Float16* wp     = (_Float16*)(ws + O_WP);
    float*    dwT    = ws + O_DWT;
    _Float16* y16    = (_Float16*)(ws + O_Y16);
    _Float16* xpad16 = (_Float16*)(ws + O_XP16);

    _Float16* wp_conv = wp;
    _Float16* wp_in   = wp + (size_t)2048 * 8;
    _Float16* wp_om   = wp + (size_t)4096 * 8;
    _Float16* wp_out  = wp + (size_t)5888 * 8;

    p0_pack<<<64, 256, 0, stream>>>(conv_w, in_proj_w, off_w, mask_w, out_proj_w, dw_w, wp, dwT, xpad16);
    gA_conv_inproj<<<NPIX / 32, 256, 0, stream>>>(x, wp_conv, wp_in, conv_b, in_proj_b, y16, xpad16);
    gF_mega<<<NPIX / 64, 512, 0, stream>>>(y16, xpad16, wp_om, wp_out, dwT, dw_b,
                                           ln_g, ln_b, off_b, mask_b, out_proj_b, out);
}